// Round 1
// baseline (398.274 us; speedup 1.0000x reference)
//
#include <hip/hip_runtime.h>
#include <cstdint>
#include <cstddef>
#include <math.h>

#define D_DIM 2048
#define H_DIM 64
#define B_TOK 8192
#define NCAT  256   // 64 k | 64 v | 64 q | 1 eta_logit | 63 zero pad

// ---------------- pack weights: Wcat[d][n], n in [0,256) ----------------
__global__ __launch_bounds__(256) void pack_w(const float* __restrict__ Wk,
                                              const float* __restrict__ Wv,
                                              const float* __restrict__ Wq,
                                              const float* __restrict__ wlr,
                                              float* __restrict__ Wcat) {
    int idx = blockIdx.x * 256 + threadIdx.x;   // grid = D_DIM blocks
    int d = idx >> 8, n = idx & 255;
    float val;
    if (n < 64)        val = Wk[d * 64 + n];
    else if (n < 128)  val = Wv[d * 64 + (n - 64)];
    else if (n < 192)  val = Wq[d * 64 + (n - 128)];
    else if (n == 192) val = wlr[d];
    else               val = 0.0f;
    Wcat[idx] = val;
}

// ---------------- GEMM1: C[8192][256] = x[8192][2048] @ Wcat[2048][256] ----
// f32 vector FMA, 64x64 tile, BK=32, 256 threads, 4x4 microtile.
__global__ __launch_bounds__(256) void gemm1(const float* __restrict__ x,
                                             const float* __restrict__ Wcat,
                                             float* __restrict__ C) {
    __shared__ float As[32][64];   // [k][m] (transposed A tile)
    __shared__ float Bs[32][64];   // [k][n]
    const int m0 = blockIdx.x * 64;
    const int n0 = blockIdx.y * 64;
    const int tid = threadIdx.x;
    const int tx = tid & 15, ty = tid >> 4;

    const int arow = tid >> 2;          // 0..63
    const int acol = (tid & 3) * 8;     // 0,8,16,24
    const int bkr  = tid >> 4;          // 0..15
    const int bcol = (tid & 15) * 4;    // 0..60

    float acc[4][4] = {};

    for (int k0 = 0; k0 < D_DIM; k0 += 32) {
        float4 a0 = *(const float4*)(x + (size_t)(m0 + arow) * D_DIM + k0 + acol);
        float4 a1 = *(const float4*)(x + (size_t)(m0 + arow) * D_DIM + k0 + acol + 4);
        float4 b0 = *(const float4*)(Wcat + (size_t)(k0 + bkr)      * NCAT + n0 + bcol);
        float4 b1 = *(const float4*)(Wcat + (size_t)(k0 + bkr + 16) * NCAT + n0 + bcol);
        As[acol + 0][arow] = a0.x; As[acol + 1][arow] = a0.y;
        As[acol + 2][arow] = a0.z; As[acol + 3][arow] = a0.w;
        As[acol + 4][arow] = a1.x; As[acol + 5][arow] = a1.y;
        As[acol + 6][arow] = a1.z; As[acol + 7][arow] = a1.w;
        *(float4*)&Bs[bkr][bcol]      = b0;
        *(float4*)&Bs[bkr + 16][bcol] = b1;
        __syncthreads();
        #pragma unroll
        for (int k = 0; k < 32; ++k) {
            float4 a = *(const float4*)&As[k][ty * 4];
            float4 b = *(const float4*)&Bs[k][tx * 4];
            float ar[4] = {a.x, a.y, a.z, a.w};
            float br[4] = {b.x, b.y, b.z, b.w};
            #pragma unroll
            for (int i = 0; i < 4; ++i)
                #pragma unroll
                for (int j = 0; j < 4; ++j)
                    acc[i][j] = fmaf(ar[i], br[j], acc[i][j]);
        }
        __syncthreads();
    }
    #pragma unroll
    for (int i = 0; i < 4; ++i) {
        float4 o = make_float4(acc[i][0], acc[i][1], acc[i][2], acc[i][3]);
        *(float4*)(C + (size_t)(m0 + ty * 4 + i) * NCAT + n0 + tx * 4) = o;
    }
}

// ---------------- per-token TTT step: one wave per token --------------------
// Computes ssl_loss, W_new (rank-1 update), and u = q + LN(W_new q).
__device__ __forceinline__ float wsum64(float x) {
    #pragma unroll
    for (int o = 32; o > 0; o >>= 1) x += __shfl_xor(x, o, 64);
    return x;
}

__global__ __launch_bounds__(256) void ttt_step(
    const float* __restrict__ C, const float* __restrict__ W_init,
    const float* __restrict__ bk_, const float* __restrict__ bv_,
    const float* __restrict__ bq_, const float* __restrict__ blr_,
    const float* __restrict__ ln_g, const float* __restrict__ ln_b,
    float* __restrict__ Wnew_out, float* __restrict__ ssl_out,
    float* __restrict__ u_out) {
    __shared__ float Wi[64][65];            // padded: bank = (r + c) % 32
    __shared__ float sk[4][64], sq[4][64], sdh[4][64];
    const int tid = threadIdx.x;
    const int w = tid >> 6, lane = tid & 63;

    for (int i = tid; i < 4096; i += 256)
        Wi[i >> 6][i & 63] = W_init[i];

    const int t = blockIdx.x * 4 + w;
    const float* Ct = C + (size_t)t * NCAT;
    float k = Ct[lane] + bk_[lane];
    float v = Ct[64 + lane] + bv_[lane];
    float q = Ct[128 + lane] + bq_[lane];
    float elog = Ct[192] + blr_[0];
    float eta = 1.0f / (1.0f + expf(-elog));

    sk[w][lane] = k;
    sq[w][lane] = q;
    __syncthreads();

    float h = 0.0f, hq = 0.0f;
    #pragma unroll
    for (int j = 0; j < 64; ++j) {
        float wj = Wi[lane][j];
        h  = fmaf(wj, sk[w][j], h);
        hq = fmaf(wj, sq[w][j], hq);
    }

    const float g = ln_g[lane], bb = ln_b[lane];
    // LN(h) forward
    float m1  = wsum64(h) * (1.0f / 64.0f);
    float hc  = h - m1;
    float var1 = wsum64(hc * hc) * (1.0f / 64.0f);
    float rs1 = rsqrtf(var1 + 1e-6f);
    float hhat = hc * rs1;
    float pred = k + hhat * g + bb;
    float diff = pred - v;
    float ssl = wsum64(diff * diff) * (1.0f / 64.0f);
    // LN backward -> dh (grad wrt h); grad_W = outer(dh, k)
    float dhhat = (2.0f / 64.0f) * diff * g;
    float s1 = wsum64(dhhat) * (1.0f / 64.0f);
    float s2 = wsum64(dhhat * hhat) * (1.0f / 64.0f);
    float dh = rs1 * (dhhat - s1 - hhat * s2);
    sdh[w][lane] = dh;

    // z path: W_new q = hq - eta*(k.q)*dh, then u = q + LN(.)
    float kq = wsum64(k * q);
    float wq = hq - eta * kq * dh;
    float m2 = wsum64(wq) * (1.0f / 64.0f);
    float wc = wq - m2;
    float var2 = wsum64(wc * wc) * (1.0f / 64.0f);
    float rs2 = rsqrtf(var2 + 1e-6f);
    float u = q + wc * rs2 * g + bb;
    u_out[(size_t)t * 64 + lane] = u;
    if (lane == 0) ssl_out[t] = ssl;

    // W_new[i][j] = Wi[i][j] - eta*dh[i]*k[j]; coalesced float4 rows
    float* Wout = Wnew_out + (size_t)t * 4096;
    const int r_off = lane >> 4;        // 0..3
    const int c4 = (lane & 15) * 4;     // 0..60
    #pragma unroll
    for (int rr = 0; rr < 16; ++rr) {
        int r = rr * 4 + r_off;
        float e = eta * sdh[w][r];
        float4 o;
        o.x = Wi[r][c4 + 0] - e * sk[w][c4 + 0];
        o.y = Wi[r][c4 + 1] - e * sk[w][c4 + 1];
        o.z = Wi[r][c4 + 2] - e * sk[w][c4 + 2];
        o.w = Wi[r][c4 + 3] - e * sk[w][c4 + 3];
        *(float4*)(Wout + r * 64 + c4) = o;
    }
}

// ---------------- GEMM2: z[8192][2048] = u[8192][64] @ Wo[64][2048] + bo ----
__global__ __launch_bounds__(256) void gemm2(const float* __restrict__ u,
                                             const float* __restrict__ Wo,
                                             const float* __restrict__ bo,
                                             float* __restrict__ z) {
    __shared__ float Ut[64][64];   // [k][m]
    __shared__ float Ws[64][64];   // [k][n]
    const int m0 = blockIdx.x * 64;
    const int n0 = blockIdx.y * 64;
    const int tid = threadIdx.x;
    const int tx = tid & 15, ty = tid >> 4;

    {
        int row = tid >> 2, c0 = (tid & 3) * 16;
        const float4* src = (const float4*)(u + (size_t)(m0 + row) * 64 + c0);
        #pragma unroll
        for (int f = 0; f < 4; ++f) {
            float4 a = src[f];
            Ut[c0 + f * 4 + 0][row] = a.x;
            Ut[c0 + f * 4 + 1][row] = a.y;
            Ut[c0 + f * 4 + 2][row] = a.z;
            Ut[c0 + f * 4 + 3][row] = a.w;
        }
        int kr = tid >> 2;
        const float4* wsrc = (const float4*)(Wo + (size_t)kr * D_DIM + n0 + c0);
        #pragma unroll
        for (int f = 0; f < 4; ++f)
            *(float4*)&Ws[kr][c0 + f * 4] = wsrc[f];
    }
    __syncthreads();

    float acc[4][4] = {};
    #pragma unroll
    for (int k = 0; k < 64; ++k) {
        float4 a = *(const float4*)&Ut[k][ty * 4];
        float4 b = *(const float4*)&Ws[k][tx * 4];
        float ar[4] = {a.x, a.y, a.z, a.w};
        float br[4] = {b.x, b.y, b.z, b.w};
        #pragma unroll
        for (int i = 0; i < 4; ++i)
            #pragma unroll
            for (int j = 0; j < 4; ++j)
                acc[i][j] = fmaf(ar[i], br[j], acc[i][j]);
    }
    float4 bo4 = *(const float4*)(bo + n0 + tx * 4);
    #pragma unroll
    for (int i = 0; i < 4; ++i) {
        float4 o = make_float4(acc[i][0] + bo4.x, acc[i][1] + bo4.y,
                               acc[i][2] + bo4.z, acc[i][3] + bo4.w);
        *(float4*)(z + (size_t)(m0 + ty * 4 + i) * D_DIM + n0 + tx * 4) = o;
    }
}

// ---------------------------------------------------------------------------
extern "C" void kernel_launch(void* const* d_in, const int* in_sizes, int n_in,
                              void* d_out, int out_size, void* d_ws, size_t ws_size,
                              hipStream_t stream) {
    const float* x    = (const float*)d_in[0];
    const float* Wk   = (const float*)d_in[1];
    const float* bk   = (const float*)d_in[2];
    const float* Wv   = (const float*)d_in[3];
    const float* bv   = (const float*)d_in[4];
    const float* Wq   = (const float*)d_in[5];
    const float* bq   = (const float*)d_in[6];
    const float* Wo   = (const float*)d_in[7];
    const float* bo   = (const float*)d_in[8];
    const float* ln_g = (const float*)d_in[9];
    const float* ln_b = (const float*)d_in[10];
    const float* wlr  = (const float*)d_in[11];
    const float* blr  = (const float*)d_in[12];
    const float* Wini = (const float*)d_in[13];

    float* z_out   = (float*)d_out;                                   // 8192*2048
    float* Wn_out  = z_out + (size_t)B_TOK * D_DIM;                   // 8192*64*64
    float* ssl_out = Wn_out + (size_t)B_TOK * H_DIM * H_DIM;          // 8192

    float* Wcat = (float*)d_ws;                       // 2048*256
    float* C    = Wcat + (size_t)D_DIM * NCAT;        // 8192*256
    float* u    = C + (size_t)B_TOK * NCAT;           // 8192*64

    pack_w<<<D_DIM, 256, 0, stream>>>(Wk, Wv, Wq, wlr, Wcat);
    gemm1<<<dim3(B_TOK / 64, NCAT / 64), 256, 0, stream>>>(x, Wcat, C);
    ttt_step<<<B_TOK / 4, 256, 0, stream>>>(C, Wini, bk, bv, bq, blr,
                                            ln_g, ln_b, Wn_out, ssl_out, u);
    gemm2<<<dim3(B_TOK / 64, D_DIM / 64), 256, 0, stream>>>(u, Wo, bo, z_out);
}

// Round 8
// 345.718 us; speedup vs baseline: 1.1520x; 1.1520x over previous
//
#include <hip/hip_runtime.h>
#include <cstdint>
#include <cstddef>
#include <math.h>

#define D_DIM 2048
#define H_DIM 64
#define B_TOK 8192
#define NCAT  256   // 64 k | 64 v | 64 q | 1 eta_logit | 63 zero pad

typedef short s16x8 __attribute__((ext_vector_type(8)));
typedef float f32x4 __attribute__((ext_vector_type(4)));

// ---------------- pack: Wtg hi/lo, granule-major --------------------------
// Granule (Gd, n): 8 bf16 (16 B) = Wcat[Gd*8 .. Gd*8+8)[n], split hi/lo.
// Flat granule index = Gd*256 + n,  Gd in [0,256), n in [0,256).
__global__ __launch_bounds__(256) void pack_w2(const float* __restrict__ Wk,
                                               const float* __restrict__ Wv,
                                               const float* __restrict__ Wq,
                                               const float* __restrict__ wlr,
                                               uint4* __restrict__ Wh,
                                               uint4* __restrict__ Wl) {
    int id = blockIdx.x * 256 + threadIdx.x;   // grid = 256 blocks
    int Gd = id >> 8, n = id & 255;
    unsigned short hb[8], lb[8];
    #pragma unroll
    for (int j = 0; j < 8; ++j) {
        int d = Gd * 8 + j;
        float val;
        if (n < 64)        val = Wk[d * 64 + n];
        else if (n < 128)  val = Wv[d * 64 + (n - 64)];
        else if (n < 192)  val = Wq[d * 64 + (n - 128)];
        else if (n == 192) val = wlr[d];
        else               val = 0.0f;
        unsigned int xb = __float_as_uint(val);
        hb[j] = (unsigned short)(xb >> 16);
        float hf = __uint_as_float(xb & 0xFFFF0000u);
        lb[j] = (unsigned short)(__float_as_uint(val - hf) >> 16);
    }
    uint4 oh, ol;
    oh.x = hb[0] | ((unsigned int)hb[1] << 16);
    oh.y = hb[2] | ((unsigned int)hb[3] << 16);
    oh.z = hb[4] | ((unsigned int)hb[5] << 16);
    oh.w = hb[6] | ((unsigned int)hb[7] << 16);
    ol.x = lb[0] | ((unsigned int)lb[1] << 16);
    ol.y = lb[2] | ((unsigned int)lb[3] << 16);
    ol.z = lb[4] | ((unsigned int)lb[5] << 16);
    ol.w = lb[6] | ((unsigned int)lb[7] << 16);
    Wh[id] = oh;
    Wl[id] = ol;
}

// ---------------- GEMM1: C[8192][256] = x @ Wcat via bf16x3 MFMA ----------
__device__ __forceinline__ void cvt_hl(const float4& a, const float4& b,
                                       s16x8& h, s16x8& l) {
    float v[8] = {a.x, a.y, a.z, a.w, b.x, b.y, b.z, b.w};
    #pragma unroll
    for (int j = 0; j < 8; ++j) {
        unsigned int xb = __float_as_uint(v[j]);
        h[j] = (short)(xb >> 16);
        float hf = __uint_as_float(xb & 0xFFFF0000u);
        l[j] = (short)(__float_as_uint(v[j] - hf) >> 16);
    }
}

#define MFMA __builtin_amdgcn_mfma_f32_16x16x32_bf16

#define GBODY(K, CUR, NXT, BP0, BP1, BN0, BN1, AP0, AP1, AP2, AP3, AN0, AN1, AN2, AN3) \
  { \
    const s16x8* BHp = (const s16x8*)&Bh[CUR][0]; \
    const s16x8* BLp = (const s16x8*)&Bl[CUR][0]; \
    s16x8 bh0 = BHp[bgi], bh1 = BHp[bgi + 16]; \
    s16x8 bl0 = BLp[bgi], bl1 = BLp[bgi + 16]; \
    Bh[NXT][tid] = BP0; Bl[NXT][tid] = BP1; \
    int kb2 = (((K) + 2 <= 63) ? (K) + 2 : 63) * 4; \
    BN0 = Wh[kb2 * 256 + srcoff]; \
    BN1 = Wl[kb2 * 256 + srcoff]; \
    int ka = (((K) + 1 <= 63) ? (K) + 1 : 63) * 32; \
    AN0 = *(const float4*)(ax0 + ka);     AN1 = *(const float4*)(ax0 + ka + 4); \
    AN2 = *(const float4*)(ax1 + ka);     AN3 = *(const float4*)(ax1 + ka + 4); \
    s16x8 ah0, al0, ah1, al1; \
    cvt_hl(AP0, AP1, ah0, al0); \
    cvt_hl(AP2, AP3, ah1, al1); \
    acc00 = MFMA(ah0, bh0, acc00, 0, 0, 0); \
    acc01 = MFMA(ah0, bh1, acc01, 0, 0, 0); \
    acc10 = MFMA(ah1, bh0, acc10, 0, 0, 0); \
    acc11 = MFMA(ah1, bh1, acc11, 0, 0, 0); \
    acc00 = MFMA(ah0, bl0, acc00, 0, 0, 0); \
    acc01 = MFMA(ah0, bl1, acc01, 0, 0, 0); \
    acc10 = MFMA(ah1, bl0, acc10, 0, 0, 0); \
    acc11 = MFMA(ah1, bl1, acc11, 0, 0, 0); \
    acc00 = MFMA(al0, bh0, acc00, 0, 0, 0); \
    acc01 = MFMA(al0, bh1, acc01, 0, 0, 0); \
    acc10 = MFMA(al1, bh0, acc10, 0, 0, 0); \
    acc11 = MFMA(al1, bh1, acc11, 0, 0, 0); \
    __syncthreads(); \
  }

__global__ __launch_bounds__(256) void gemm1m(const float* __restrict__ x,
                                              const uint4* __restrict__ Wh,
                                              const uint4* __restrict__ Wl,
                                              float* __restrict__ C) {
    __shared__ uint4 Bh[2][256];   // [buf][G*64+n] granule-major, 4 KB each
    __shared__ uint4 Bl[2][256];
    const int tid  = threadIdx.x;
    const int lane = tid & 63;
    const int wave = tid >> 6;
    const int wm = wave >> 1, wn = wave & 1;   // wave tile 32(m) x 32(n)
    const int l15 = lane & 15, l4 = lane >> 4;
    const int m0 = blockIdx.x * 64;
    const int n0 = blockIdx.y * 64;

    const float* ax0 = x + (size_t)(m0 + wm * 32 + l15) * D_DIM + l4 * 8;
    const float* ax1 = ax0 + (size_t)16 * D_DIM;
    const int srcoff = (tid >> 6) * 256 + n0 + (tid & 63); // staged granule src
    const int bgi = l4 * 64 + wn * 32 + l15;               // B-frag granule idx

    f32x4 z4 = {0.f, 0.f, 0.f, 0.f};
    f32x4 acc00 = z4, acc01 = z4, acc10 = z4, acc11 = z4;

    // prologue: stage B(0) into buf0; prefetch B(1), A(0)
    {
        uint4 t0 = Wh[srcoff], t1 = Wl[srcoff];
        Bh[0][tid] = t0; Bl[0][tid] = t1;
    }
    float4 apA0 = *(const float4*)(ax0);
    float4 apA1 = *(const float4*)(ax0 + 4);
    float4 apA2 = *(const float4*)(ax1);
    float4 apA3 = *(const float4*)(ax1 + 4);
    uint4 bpA0 = Wh[4 * 256 + srcoff];
    uint4 bpA1 = Wl[4 * 256 + srcoff];
    float4 apB0, apB1, apB2, apB3;
    uint4  bpB0, bpB1;
    __syncthreads();

    #pragma unroll 1
    for (int k = 0; k < 64; k += 2) {
        GBODY(k,     0, 1, bpA0, bpA1, bpB0, bpB1,
              apA0, apA1, apA2, apA3, apB0, apB1, apB2, apB3)
        GBODY(k + 1, 1, 0, bpB0, bpB1, bpA0, bpA1,
              apB0, apB1, apB2, apB3, apA0, apA1, apA2, apA3)
    }

    // epilogue: C/D map col = lane&15, row = (lane>>4)*4 + r  [m89-verified]
    float* cp = C + (size_t)(m0 + wm * 32 + l4 * 4) * NCAT + n0 + wn * 32 + l15;
    #pragma unroll
    for (int r = 0; r < 4; ++r) {
        cp[(size_t)r * NCAT +  0]        = acc00[r];
        cp[(size_t)r * NCAT + 16]        = acc01[r];
        cp[(size_t)(16 + r) * NCAT +  0] = acc10[r];
        cp[(size_t)(16 + r) * NCAT + 16] = acc11[r];
    }
}

// ---------------- per-token TTT step: one wave per token --------------------
__device__ __forceinline__ float wsum64(float x) {
    #pragma unroll
    for (int o = 32; o > 0; o >>= 1) x += __shfl_xor(x, o, 64);
    return x;
}

__global__ __launch_bounds__(256) void ttt_step(
    const float* __restrict__ C, const float* __restrict__ W_init,
    const float* __restrict__ bk_, const float* __restrict__ bv_,
    const float* __restrict__ bq_, const float* __restrict__ blr_,
    const float* __restrict__ ln_g, const float* __restrict__ ln_b,
    float* __restrict__ Wnew_out, float* __restrict__ ssl_out,
    float* __restrict__ u_out) {
    __shared__ float Wi[64][65];
    __shared__ float sk[4][64], sq[4][64], sdh[4][64];
    const int tid = threadIdx.x;
    const int w = tid >> 6, lane = tid & 63;

    for (int i = tid; i < 4096; i += 256)
        Wi[i >> 6][i & 63] = W_init[i];

    const int t = blockIdx.x * 4 + w;
    const float* Ct = C + (size_t)t * NCAT;
    float k = Ct[lane] + bk_[lane];
    float v = Ct[64 + lane] + bv_[lane];
    float q = Ct[128 + lane] + bq_[lane];
    float elog = Ct[192] + blr_[0];
    float eta = 1.0f / (1.0f + expf(-elog));

    sk[w][lane] = k;
    sq[w][lane] = q;
    __syncthreads();

    float h = 0.0f, hq = 0.0f;
    #pragma unroll
    for (int j = 0; j < 64; ++j) {
        float wj = Wi[lane][j];
        h  = fmaf(wj, sk[w][j], h);
        hq = fmaf(wj, sq[w][j], hq);
    }

    const float g = ln_g[lane], bb = ln_b[lane];
    float m1  = wsum64(h) * (1.0f / 64.0f);
    float hc  = h - m1;
    float var1 = wsum64(hc * hc) * (1.0f / 64.0f);
    float rs1 = rsqrtf(var1 + 1e-6f);
    float hhat = hc * rs1;
    float pred = k + hhat * g + bb;
    float diff = pred - v;
    float ssl = wsum64(diff * diff) * (1.0f / 64.0f);
    float dhhat = (2.0f / 64.0f) * diff * g;
    float s1 = wsum64(dhhat) * (1.0f / 64.0f);
    float s2 = wsum64(dhhat * hhat) * (1.0f / 64.0f);
    float dh = rs1 * (dhhat - s1 - hhat * s2);
    sdh[w][lane] = dh;

    float kq = wsum64(k * q);
    float wq = hq - eta * kq * dh;
    float m2 = wsum64(wq) * (1.0f / 64.0f);
    float wc = wq - m2;
    float var2 = wsum64(wc * wc) * (1.0f / 64.0f);
    float rs2 = rsqrtf(var2 + 1e-6f);
    float u = q + wc * rs2 * g + bb;
    u_out[(size_t)t * 64 + lane] = u;
    if (lane == 0) ssl_out[t] = ssl;

    float* Wout = Wnew_out + (size_t)t * 4096;
    const int r_off = lane >> 4;
    const int c4 = (lane & 15) * 4;
    #pragma unroll
    for (int rr = 0; rr < 16; ++rr) {
        int r = rr * 4 + r_off;
        float e = eta * sdh[w][r];
        float4 o;
        o.x = Wi[r][c4 + 0] - e * sk[w][c4 + 0];
        o.y = Wi[r][c4 + 1] - e * sk[w][c4 + 1];
        o.z = Wi[r][c4 + 2] - e * sk[w][c4 + 2];
        o.w = Wi[r][c4 + 3] - e * sk[w][c4 + 3];
        *(float4*)(Wout + r * 64 + c4) = o;
    }
}

// ---------------- GEMM2: z[8192][2048] = u[8192][64] @ Wo[64][2048] + bo ----
__global__ __launch_bounds__(256) void gemm2(const float* __restrict__ u,
                                             const float* __restrict__ Wo,
                                             const float* __restrict__ bo,
                                             float* __restrict__ z) {
    __shared__ float Ut[64][64];
    __shared__ float Ws[64][64];
    const int m0 = blockIdx.x * 64;
    const int n0 = blockIdx.y * 64;
    const int tid = threadIdx.x;
    const int tx = tid & 15, ty = tid >> 4;

    {
        int row = tid >> 2, c0 = (tid & 3) * 16;
        const float4* src = (const float4*)(u + (size_t)(m0 + row) * 64 + c0);
        #pragma unroll
        for (int f = 0; f < 4; ++f) {
            float4 a = src[f];
            Ut[c0 + f * 4 + 0][row] = a.x;
            Ut[c0 + f * 4 + 1][row] = a.y;
            Ut[c0 + f * 4 + 2][row] = a.z;
            Ut[c0 + f * 4 + 3][row] = a.w;
        }
        int kr = tid >> 2;
        const float4* wsrc = (const float4*)(Wo + (size_t)kr * D_DIM + n0 + c0);
        #pragma unroll
        for (int f = 0; f < 4; ++f)
            *(float4*)&Ws[kr][c0 + f * 4] = wsrc[f];
    }
    __syncthreads();

    float acc[4][4] = {};
    #pragma unroll
    for (int k = 0; k < 64; ++k) {
        float4 a = *(const float4*)&Ut[k][ty * 4];
        float4 b = *(const float4*)&Ws[k][tx * 4];
        float ar[4] = {a.x, a.y, a.z, a.w};
        float br[4] = {b.x, b.y, b.z, b.w};
        #pragma unroll
        for (int i = 0; i < 4; ++i)
            #pragma unroll
            for (int j = 0; j < 4; ++j)
                acc[i][j] = fmaf(ar[i], br[j], acc[i][j]);
    }
    float4 bo4 = *(const float4*)(bo + n0 + tx * 4);
    #pragma unroll
    for (int i = 0; i < 4; ++i) {
        float4 o = make_float4(acc[i][0] + bo4.x, acc[i][1] + bo4.y,
                               acc[i][2] + bo4.z, acc[i][3] + bo4.w);
        *(float4*)(z + (size_t)(m0 + ty * 4 + i) * D_DIM + n0 + tx * 4) = o;
    }
}

// ---------------------------------------------------------------------------
extern "C" void kernel_launch(void* const* d_in, const int* in_sizes, int n_in,
                              void* d_out, int out_size, void* d_ws, size_t ws_size,
                              hipStream_t stream) {
    const float* x    = (const float*)d_in[0];
    const float* Wk   = (const float*)d_in[1];
    const float* bk   = (const float*)d_in[2];
    const float* Wv   = (const float*)d_in[3];
    const float* bv   = (const float*)d_in[4];
    const float* Wq   = (const float*)d_in[5];
    const float* bq   = (const float*)d_in[6];
    const float* Wo   = (const float*)d_in[7];
    const float* bo   = (const float*)d_in[8];
    const float* ln_g = (const float*)d_in[9];
    const float* ln_b = (const float*)d_in[10];
    const float* wlr  = (const float*)d_in[11];
    const float* blr  = (const float*)d_in[12];
    const float* Wini = (const float*)d_in[13];

    float* z_out   = (float*)d_out;
    float* Wn_out  = z_out + (size_t)B_TOK * D_DIM;
    float* ssl_out = Wn_out + (size_t)B_TOK * H_DIM * H_DIM;

    uint4* Wh = (uint4*)d_ws;                       // 65536 granules = 1 MB
    uint4* Wl = Wh + 65536;                         // 1 MB
    float* C  = (float*)(Wl + 65536);               // 8192*256 f32 = 8 MB
    float* u  = C + (size_t)B_TOK * NCAT;           // 8192*64 f32 = 2 MB

    pack_w2<<<256, 256, 0, stream>>>(Wk, Wv, Wq, wlr, Wh, Wl);
    gemm1m<<<dim3(B_TOK / 64, NCAT / 64), 256, 0, stream>>>(x, Wh, Wl, C);
    ttt_step<<<B_TOK / 4, 256, 0, stream>>>(C, Wini, bk, bv, bq, blr,
                                            ln_g, ln_b, Wn_out, ssl_out, u);
    gemm2<<<dim3(B_TOK / 64, D_DIM / 64), 256, 0, stream>>>(u, Wo, bo, z_out);
}